// Round 1
// baseline (2359.004 us; speedup 1.0000x reference)
//
#include <hip/hip_runtime.h>
#include <hip/hip_bf16.h>
#include <math.h>

// Problem dims
#define B_   32
#define NO_  100
#define NE_  600
#define NK_  1000
#define KE_  1000
#define L_   8
#define R_   8
#define H_   512
#define IMG_ 2048
#define LOC_ 5
#define EMB_ 300
#define MID_ 512
#define C_   3000
#define PAD_ 1

#define NN_  (NO_ + NK_)   // 1100 node keys
#define NEK_ (NE_ + KE_)   // 1600 edge keys

__device__ __forceinline__ float4 ldf4(const float* p) { return *(const float4*)p; }
__device__ __forceinline__ void stf4(float* p, float4 v) { *(float4*)p = v; }

// ---------------------------------------------------------------------------
// Register-blocked GEMM tile: 16 rows x 512 cols per block, 256 threads.
// Thread (rg = tid>>6, cg = tid&63) computes 4 rows x 8 cols.
// A in LDS, laid out [16][ALD]; reads are wave-broadcast ds_read_b128 (free).
// W read from global, coalesced float4 pairs (L1/L2 resident).
template<int K, int ALD>
__device__ __forceinline__ void gemm_acc(const float* __restrict__ As,
                                         const float* __restrict__ W,
                                         float acc[4][8], int rg, int cg)
{
    for (int e = 0; e < K; e += 4) {
        float av[4][4];
#pragma unroll
        for (int rr = 0; rr < 4; ++rr)
            *(float4*)av[rr] = ldf4(&As[(rg * 4 + rr) * ALD + e]);
#pragma unroll
        for (int j = 0; j < 4; ++j) {
            const float* wp = W + (size_t)(e + j) * H_ + cg * 8;
            float w[8];
            *(float4*)w       = ldf4(wp);
            *(float4*)(w + 4) = ldf4(wp + 4);
#pragma unroll
            for (int rr = 0; rr < 4; ++rr)
#pragma unroll
                for (int cc = 0; cc < 8; ++cc)
                    acc[rr][cc] = fmaf(av[rr][j], w[cc], acc[rr][cc]);
        }
    }
}

// Stage one 512-float row chunk into LDS; call with r = tid>>4 row, l = tid&15.
// 16 lanes per row -> 256B-coalesced global reads.
__device__ __forceinline__ void stage_row(float* AsRow, const float* src, int l)
{
#pragma unroll
    for (int j = 0; j < 8; ++j) {
        int f4i = l + j * 16;
        stf4(&AsRow[f4i * 4], ldf4(src + f4i * 4));
    }
}

// ---------------------------------------------------------------------------
// lang_encode: masked-mean-pool of embeddings + tanh(pooled @ W_lang + b).
// 16 rows / block. Also emits "any token != PAD" mask when requested.
__global__ __launch_bounds__(256) void lang_enc_kernel(
    const int* __restrict__ tokens, int tok_stride, int tok_off,
    const float* __restrict__ embed, const float* __restrict__ W,
    const float* __restrict__ bias,
    float* __restrict__ out, int rows_per_b, long out_bstride, long out_roff,
    float* __restrict__ maskout, int nrows)
{
    __shared__ float Ps[16][304];   // pooled, padded to 304 for f4 alignment
    __shared__ int   toks[16][L_];
    __shared__ float rinv[16];

    int tid  = threadIdx.x;
    int base = blockIdx.x * 16;

    if (tid < 16 * L_) {
        int r = tid >> 3, t = tid & 7;
        int i = base + r;
        toks[r][t] = (i < nrows) ? tokens[tok_off + (long)i * tok_stride + t] : PAD_;
    }
    __syncthreads();
    if (tid < 16) {
        int c = 0;
#pragma unroll
        for (int t = 0; t < L_; ++t) c += (toks[tid][t] != PAD_);
        rinv[tid] = 1.0f / fmaxf((float)c, 1.0f);
        int i = base + tid;
        if (maskout && i < nrows) maskout[i] = (c > 0) ? 1.0f : 0.0f;
    }
    __syncthreads();

    // pooled: 16 rows x 75 float4 chunks of EMB=300
    for (int task = tid; task < 16 * 75; task += 256) {
        int r  = task / 75;
        int e4 = (task - r * 75) * 4;
        float sx = 0.f, sy = 0.f, sz = 0.f, sw = 0.f;
#pragma unroll
        for (int t = 0; t < L_; ++t) {
            int tok = toks[r][t];
            if (tok != PAD_) {
                float4 v = ldf4(&embed[(long)tok * EMB_ + e4]);
                sx += v.x; sy += v.y; sz += v.z; sw += v.w;
            }
        }
        float inv = rinv[r];
        float4 o; o.x = sx * inv; o.y = sy * inv; o.z = sz * inv; o.w = sw * inv;
        stf4(&Ps[r][e4], o);
    }
    __syncthreads();

    int rg = tid >> 6, cg = tid & 63;
    float acc[4][8];
#pragma unroll
    for (int rr = 0; rr < 4; ++rr)
#pragma unroll
        for (int cc = 0; cc < 8; ++cc) acc[rr][cc] = 0.f;

    gemm_acc<EMB_, 304>(&Ps[0][0], W, acc, rg, cg);

    float bv[8];
    *(float4*)bv       = ldf4(bias + cg * 8);
    *(float4*)(bv + 4) = ldf4(bias + cg * 8 + 4);

#pragma unroll
    for (int rr = 0; rr < 4; ++rr) {
        int i = base + rg * 4 + rr;
        if (i >= nrows) continue;
        int b = i / rows_per_b;
        int k = i - b * rows_per_b;
        float* op = out + (long)b * out_bstride + out_roff + (long)k * H_ + cg * 8;
        float res[8];
#pragma unroll
        for (int cc = 0; cc < 8; ++cc) res[cc] = tanhf(acc[rr][cc] + bv[cc]);
        stf4(op, *(float4*)res);
        stf4(op + 4, *(float4*)(res + 4));
    }
}

// ---------------------------------------------------------------------------
// img_f = img_feat @ W_img + b_img ; node_keys[:, :NO] = img_f + img_loc@W_loc + b_loc
__global__ __launch_bounds__(256) void img_node_kernel(
    const float* __restrict__ img_feat, const float* __restrict__ img_loc,
    const float* __restrict__ W_img, const float* __restrict__ b_img,
    const float* __restrict__ W_loc, const float* __restrict__ b_loc,
    float* __restrict__ img_f, float* __restrict__ node_keys)
{
    __shared__ float As[16 * 512];
    int tid  = threadIdx.x;
    int base = blockIdx.x * 16;              // rows i = b*NO + o, total 3200
    int rg = tid >> 6, cg = tid & 63;
    float acc[4][8];
#pragma unroll
    for (int rr = 0; rr < 4; ++rr)
#pragma unroll
        for (int cc = 0; cc < 8; ++cc) acc[rr][cc] = 0.f;

    for (int k0 = 0; k0 < IMG_; k0 += 512) {
        int r = tid >> 4, l = tid & 15;
        stage_row(As + r * 512, img_feat + (long)(base + r) * IMG_ + k0, l);
        __syncthreads();
        gemm_acc<512, 512>(As, W_img + (size_t)k0 * H_, acc, rg, cg);
        __syncthreads();
    }

    float bi[8], bl[8];
    *(float4*)bi       = ldf4(b_img + cg * 8);
    *(float4*)(bi + 4) = ldf4(b_img + cg * 8 + 4);
    *(float4*)bl       = ldf4(b_loc + cg * 8);
    *(float4*)(bl + 4) = ldf4(b_loc + cg * 8 + 4);

#pragma unroll
    for (int rr = 0; rr < 4; ++rr) {
        int i = base + rg * 4 + rr;
        int b = i / NO_;
        int o = i - b * NO_;
        float res[8], nk[8];
#pragma unroll
        for (int cc = 0; cc < 8; ++cc) res[cc] = acc[rr][cc] + bi[cc];
        stf4(&img_f[(long)i * H_ + cg * 8],     *(float4*)res);
        stf4(&img_f[(long)i * H_ + cg * 8 + 4], *(float4*)(res + 4));
#pragma unroll
        for (int cc = 0; cc < 8; ++cc) nk[cc] = res[cc] + bl[cc];
#pragma unroll
        for (int j = 0; j < LOC_; ++j) {
            float lj = img_loc[(long)i * LOC_ + j];
            const float* wl = W_loc + (size_t)j * H_ + cg * 8;
            float wv[8];
            *(float4*)wv       = ldf4(wl);
            *(float4*)(wv + 4) = ldf4(wl + 4);
#pragma unroll
            for (int cc = 0; cc < 8; ++cc) nk[cc] = fmaf(lj, wv[cc], nk[cc]);
        }
        float* op = node_keys + (long)b * (NN_ * H_) + (long)o * H_ + cg * 8;
        stf4(op,     *(float4*)nk);
        stf4(op + 4, *(float4*)(nk + 4));
    }
}

// ---------------------------------------------------------------------------
// edge_keys[:, :NE] = [img_f[id1] | img_f[id2]] @ W_rel + b_rel
__global__ __launch_bounds__(256) void img_edge_kernel(
    const float* __restrict__ img_f, const int* __restrict__ id1,
    const int* __restrict__ id2, const float* __restrict__ W_rel,
    const float* __restrict__ b_rel, float* __restrict__ edge_keys)
{
    __shared__ float As[16 * 512];
    int tid  = threadIdx.x;
    int base = blockIdx.x * 16;              // rows i = b*NE + e, total 19200
    int rg = tid >> 6, cg = tid & 63;
    float acc[4][8];
#pragma unroll
    for (int rr = 0; rr < 4; ++rr)
#pragma unroll
        for (int cc = 0; cc < 8; ++cc) acc[rr][cc] = 0.f;

    for (int half = 0; half < 2; ++half) {
        int r = tid >> 4, l = tid & 15;
        int i = base + r;
        int b = i / NE_;
        int id = (half ? id2 : id1)[i];
        stage_row(As + r * 512, img_f + ((long)b * NO_ + id) * H_, l);
        __syncthreads();
        gemm_acc<512, 512>(As, W_rel + (size_t)half * 512 * H_, acc, rg, cg);
        __syncthreads();
    }

    float bv[8];
    *(float4*)bv       = ldf4(b_rel + cg * 8);
    *(float4*)(bv + 4) = ldf4(b_rel + cg * 8 + 4);
#pragma unroll
    for (int rr = 0; rr < 4; ++rr) {
        int i = base + rg * 4 + rr;
        int b = i / NE_;
        int e = i - b * NE_;
        float res[8];
#pragma unroll
        for (int cc = 0; cc < 8; ++cc) res[cc] = acc[rr][cc] + bv[cc];
        float* op = edge_keys + (long)b * (NEK_ * H_) + (long)e * H_ + cg * 8;
        stf4(op,     *(float4*)res);
        stf4(op + 4, *(float4*)(res + 4));
    }
}

// ---------------------------------------------------------------------------
// Fused: kp = keys @ Wk, then s = sum_m tanh(qp[b,m] + kp[n,m]) * v[m] (+ mask)
// Only program node r = R-1 is needed, so qp is [B,H].
template<int N, bool MASK>
__global__ __launch_bounds__(256) void score_kernel(
    const float* __restrict__ keys, const float* __restrict__ Wk,
    const float* __restrict__ qp, const float* __restrict__ vvec,
    const float* __restrict__ maskbuf, float* __restrict__ sout)
{
    __shared__ float As[16 * 512];
    int tid  = threadIdx.x;
    int base = blockIdx.x * 16;              // rows i = b*N + n
    int rg = tid >> 6, cg = tid & 63;
    float acc[4][8];
#pragma unroll
    for (int rr = 0; rr < 4; ++rr)
#pragma unroll
        for (int cc = 0; cc < 8; ++cc) acc[rr][cc] = 0.f;

    {
        int r = tid >> 4, l = tid & 15;
        stage_row(As + r * 512, keys + (long)(base + r) * H_, l);
    }
    __syncthreads();
    gemm_acc<512, 512>(As, Wk, acc, rg, cg);

    float vv[8];
    *(float4*)vv       = ldf4(vvec + cg * 8);
    *(float4*)(vv + 4) = ldf4(vvec + cg * 8 + 4);

#pragma unroll
    for (int rr = 0; rr < 4; ++rr) {
        int i = base + rg * 4 + rr;          // all lanes in wave rg share i
        int b = i / N;
        int n = i - b * N;
        const float* qpp = qp + (long)b * H_ + cg * 8;
        float qv[8];
        *(float4*)qv       = ldf4(qpp);
        *(float4*)(qv + 4) = ldf4(qpp + 4);
        float p = 0.f;
#pragma unroll
        for (int cc = 0; cc < 8; ++cc)
            p += tanhf(qv[cc] + acc[rr][cc]) * vv[cc];
#pragma unroll
        for (int d = 1; d < 64; d <<= 1) p += __shfl_xor(p, d);
        if (cg == 0) {
            float sv = p;
            if (MASK && n >= NO_) {
                if (maskbuf[(long)b * NK_ + (n - NO_)] == 0.f) sv = -1e9f;
            }
            sout[i] = sv;
        }
    }
}

// ---------------------------------------------------------------------------
// softmax over N then weighted sum of keys -> out[b, 512]. grid (B, 2).
template<bool ADD>
__global__ __launch_bounds__(256) void attend_kernel(
    const float* __restrict__ s, const float* __restrict__ keys,
    float* __restrict__ outv, int N)
{
    __shared__ float sw[NEK_];
    __shared__ float red[256];
    int b = blockIdx.x, tid = threadIdx.x;

    float lmax = -3.0e38f;
    for (int n = tid; n < N; n += 256) {
        float x = s[(long)b * N + n];
        sw[n] = x;
        lmax = fmaxf(lmax, x);
    }
    red[tid] = lmax; __syncthreads();
    for (int st = 128; st > 0; st >>= 1) {
        if (tid < st) red[tid] = fmaxf(red[tid], red[tid + st]);
        __syncthreads();
    }
    float mx = red[0]; __syncthreads();

    float lsum = 0.f;
    for (int n = tid; n < N; n += 256) {
        float e = expf(sw[n] - mx);
        sw[n] = e;
        lsum += e;
    }
    red[tid] = lsum; __syncthreads();
    for (int st = 128; st > 0; st >>= 1) {
        if (tid < st) red[tid] += red[tid + st];
        __syncthreads();
    }
    float invZ = 1.0f / red[0];

    int col = blockIdx.y * 256 + tid;
    float a = 0.f;
#pragma unroll 4
    for (int n = 0; n < N; ++n)
        a = fmaf(sw[n], keys[((long)b * N + n) * H_ + col], a);
    a *= invZ;
    if (ADD) outv[(long)b * H_ + col] += a;
    else     outv[(long)b * H_ + col] = a;
}

// ---------------------------------------------------------------------------
// out[b,c] = act( in[b,:] @ W + bias )  — grid (B, ceil(C/256))
template<int ACT>   // 0 = none, 1 = tanh
__global__ __launch_bounds__(256) void bmatvec_kernel(
    const float* __restrict__ in, const float* __restrict__ W,
    const float* __restrict__ bias, float* __restrict__ outp, int E, int C)
{
    __shared__ float ins[512];
    int b = blockIdx.x, tid = threadIdx.x;
    for (int e = tid; e < E; e += 256) ins[e] = in[(long)b * E + e];
    __syncthreads();
    int c = blockIdx.y * 256 + tid;
    if (c >= C) return;
    float a = bias ? bias[c] : 0.0f;
#pragma unroll 4
    for (int e = 0; e < E; ++e) a = fmaf(ins[e], W[(long)e * C + c], a);
    if (ACT == 1) a = tanhf(a);
    outp[(long)b * C + c] = a;
}

// ---------------------------------------------------------------------------
extern "C" void kernel_launch(void* const* d_in, const int* in_sizes, int n_in,
                              void* d_out, int out_size, void* d_ws, size_t ws_size,
                              hipStream_t stream)
{
    (void)in_sizes; (void)n_in; (void)out_size; (void)ws_size;

    const float* img_feat  = (const float*)d_in[0];
    const float* img_loc   = (const float*)d_in[1];
    const int*   id1       = (const int*)d_in[2];
    const int*   id2       = (const int*)d_in[3];
    const int*   kg_entity = (const int*)d_in[4];
    const int*   kg_edge   = (const int*)d_in[7];
    const int*   r_nodes   = (const int*)d_in[8];
    const float* embed     = (const float*)d_in[11];
    const float* W_lang    = (const float*)d_in[12];
    const float* b_lang    = (const float*)d_in[13];
    const float* W_img     = (const float*)d_in[14];
    const float* b_img     = (const float*)d_in[15];
    const float* W_loc     = (const float*)d_in[16];
    const float* b_loc     = (const float*)d_in[17];
    const float* W_rel     = (const float*)d_in[18];
    const float* b_rel     = (const float*)d_in[19];
    const float* Wq_n      = (const float*)d_in[20];
    const float* Wk_n      = (const float*)d_in[21];
    const float* v_n       = (const float*)d_in[22];
    const float* Wq_e      = (const float*)d_in[23];
    const float* Wk_e      = (const float*)d_in[24];
    const float* v_e       = (const float*)d_in[25];
    const float* W1        = (const float*)d_in[26];
    const float* b1        = (const float*)d_in[27];
    const float* W2        = (const float*)d_in[28];
    const float* b2        = (const float*)d_in[29];
    float* out = (float*)d_out;

    float* ws = (float*)d_ws;
    size_t off = 0;
    auto alloc = [&](size_t n) { float* p = ws + off; off += n; return p; };
    float* node_keys = alloc((size_t)B_ * NN_ * H_);    // 72 MB
    float* edge_keys = alloc((size_t)B_ * NEK_ * H_);   // 105 MB
    float* img_f     = alloc((size_t)B_ * NO_ * H_);    // 6.5 MB
    float* rfeat7    = alloc((size_t)B_ * H_);
    float* qp_n      = alloc((size_t)B_ * H_);
    float* qp_e      = alloc((size_t)B_ * H_);
    float* mask_kg   = alloc((size_t)B_ * NK_);
    float* s_n       = alloc((size_t)B_ * NN_);
    float* s_e       = alloc((size_t)B_ * NEK_);
    float* fin       = alloc((size_t)B_ * H_);
    float* hid       = alloc((size_t)B_ * H_);

    // r_feat, last program node only (only node_re[:, -1] reaches the output)
    lang_enc_kernel<<<(B_ + 15) / 16, 256, 0, stream>>>(
        r_nodes, R_ * L_, (R_ - 1) * L_, embed, W_lang, b_lang,
        rfeat7, 1, (long)H_, 0L, nullptr, B_);
    // qp = rfeat7 @ Wq (no bias, no act)
    bmatvec_kernel<0><<<dim3(B_, 2), 256, 0, stream>>>(rfeat7, Wq_n, nullptr, qp_n, H_, MID_);
    bmatvec_kernel<0><<<dim3(B_, 2), 256, 0, stream>>>(rfeat7, Wq_e, nullptr, qp_e, H_, MID_);
    // kg encodes -> concat sections of node_keys / edge_keys
    lang_enc_kernel<<<(B_ * NK_) / 16, 256, 0, stream>>>(
        kg_entity, L_, 0, embed, W_lang, b_lang,
        node_keys, NK_, (long)NN_ * H_, (long)NO_ * H_, mask_kg, B_ * NK_);
    lang_enc_kernel<<<(B_ * KE_) / 16, 256, 0, stream>>>(
        kg_edge, L_, 0, embed, W_lang, b_lang,
        edge_keys, KE_, (long)NEK_ * H_, (long)NE_ * H_, nullptr, B_ * KE_);
    // image branches
    img_node_kernel<<<(B_ * NO_) / 16, 256, 0, stream>>>(
        img_feat, img_loc, W_img, b_img, W_loc, b_loc, img_f, node_keys);
    img_edge_kernel<<<(B_ * NE_) / 16, 256, 0, stream>>>(
        img_f, id1, id2, W_rel, b_rel, edge_keys);
    // fused keys@Wk + additive-attention scores
    score_kernel<NN_, true><<<(B_ * NN_) / 16, 256, 0, stream>>>(
        node_keys, Wk_n, qp_n, v_n, mask_kg, s_n);
    score_kernel<NEK_, false><<<(B_ * NEK_) / 16, 256, 0, stream>>>(
        edge_keys, Wk_e, qp_e, v_e, nullptr, s_e);
    // softmax + weighted sums -> fin = node_re[:, -1] + edge_ctx[:, -1]
    attend_kernel<false><<<dim3(B_, 2), 256, 0, stream>>>(s_n, node_keys, fin, NN_);
    attend_kernel<true ><<<dim3(B_, 2), 256, 0, stream>>>(s_e, edge_keys, fin, NEK_);
    // head
    bmatvec_kernel<1><<<dim3(B_, 2), 256, 0, stream>>>(fin, W1, b1, hid, H_, MID_);
    bmatvec_kernel<0><<<dim3(B_, (C_ + 255) / 256), 256, 0, stream>>>(hid, W2, b2, out, MID_, C_);
}

// Round 2
// 770.167 us; speedup vs baseline: 3.0630x; 3.0630x over previous
//
#include <hip/hip_runtime.h>
#include <hip/hip_bf16.h>
#include <math.h>

// Problem dims
#define B_   32
#define NO_  100
#define NE_  600
#define NK_  1000
#define KE_  1000
#define L_   8
#define R_   8
#define H_   512
#define IMG_ 2048
#define LOC_ 5
#define EMB_ 300
#define MID_ 512
#define C_   3000
#define PAD_ 1

#define NN_  (NO_ + NK_)   // 1100 node keys
#define NEK_ (NE_ + KE_)   // 1600 edge keys

typedef __attribute__((ext_vector_type(8))) short bf16x8;
typedef __attribute__((ext_vector_type(4))) float f32x4;

__device__ __forceinline__ float4 ldf4(const float* p) { return *(const float4*)p; }

__device__ __forceinline__ float bf2f(short s) {
    unsigned u = ((unsigned)(unsigned short)s) << 16;
    float f; __builtin_memcpy(&f, &u, 4); return f;
}
__device__ __forceinline__ short f2bf(float f) {
    unsigned u; __builtin_memcpy(&u, &f, 4);
    u = (u + 0x7fffu + ((u >> 16) & 1u)) >> 16;   // round-nearest-even
    return (short)u;
}

// ---------------------------------------------------------------------------
// W_prep: f32 W[K][512] -> bf16 tiles [NB=4][KS][4 kg][128 nl][8 j]
// entry = W[ks*32+kg*8+j][nb*128+nl]  (zeros for k >= K)
__global__ __launch_bounds__(256) void wprep_kernel(
    const float* __restrict__ W, short* __restrict__ Wp, int K, int KS)
{
    int idx = blockIdx.x * 256 + threadIdx.x;
    int total = 4 * KS * 4 * 128;
    if (idx >= total) return;
    int nl = idx & 127;
    int kg = (idx >> 7) & 3;
    int t  = idx >> 9;            // nb*KS + ks
    int ks = t % KS;
    int nb = t / KS;
    int n = nb * 128 + nl;
    short o[8];
#pragma unroll
    for (int j = 0; j < 8; ++j) {
        int k = ks * 32 + kg * 8 + j;
        o[j] = (k < K) ? f2bf(W[(long)k * H_ + n]) : (short)0;
    }
    *(uint4*)&Wp[(long)idx * 8] = *(uint4*)o;
}

// f32 -> bf16 elementwise (n multiple of 8)
__global__ __launch_bounds__(256) void cvt_bf16_kernel(
    const float* __restrict__ src, short* __restrict__ dst, long n)
{
    long i = ((long)blockIdx.x * 256 + threadIdx.x) * 8;
    if (i >= n) return;
    float4 a = ldf4(src + i), b = ldf4(src + i + 4);
    short o[8] = { f2bf(a.x), f2bf(a.y), f2bf(a.z), f2bf(a.w),
                   f2bf(b.x), f2bf(b.y), f2bf(b.z), f2bf(b.w) };
    *(uint4*)&dst[i] = *(uint4*)o;
}

// ---------------------------------------------------------------------------
// MFMA GEMM: 128x128 tile, BK=32, 4 waves each owning 64x64.
// A: bf16 row-major (AV=0) or gathered img_f rows (AV=2, K=1024 two halves).
// B: W_prep tiles (linear copy to LDS).
// EP: 0 img_node (img_f + node_keys w/ loc), 1 img_edge, 2 score partials.
template<int AV, int EP>
__global__ __launch_bounds__(256) void mfma_gemm_kernel(
    const short* __restrict__ A, int lda, const short* __restrict__ Wp, int KS,
    const int* __restrict__ id1, const int* __restrict__ id2,
    const short* __restrict__ Agather,
    const float* __restrict__ bias, const float* __restrict__ bias2,
    const float* __restrict__ loc, const float* __restrict__ Wloc,
    const float* __restrict__ qp, const float* __restrict__ vvec,
    short* __restrict__ out0, short* __restrict__ out1,
    float* __restrict__ sout, int Nrows, int Mtot)
{
    __shared__ __align__(16) short As[4096];   // [4 kg][128 r][8]
    __shared__ __align__(16) short Bs[4096];   // [4 kg][128 n][8]
    int tid = threadIdx.x;
    int m0 = blockIdx.x * 128, nb = blockIdx.y, n0 = nb * 128;
    int w = tid >> 6, l = tid & 63, wr = w >> 1, wc = w & 1;
    int sr = tid >> 1, sh = tid & 1;

    long arow_off = 0; int r1 = 0, r2 = 0;
    if (AV == 0) {
        arow_off = (long)(m0 + sr) * lda;
    } else {
        int i = m0 + sr;
        int b = i / NE_;
        r1 = b * NO_ + id1[i];
        r2 = b * NO_ + id2[i];
    }
    const short* wslab = Wp + (long)nb * KS * 4096;

    uint4 av0, av1, bv0, bv1;
    auto loadA = [&](int ks) {
        const short* p;
        if (AV == 0) p = A + arow_off + ks * 32 + sh * 16;
        else {
            int kk = ks * 32;
            int row = (kk < 512) ? r1 : r2;
            p = Agather + (long)row * 512 + (kk & 511) + sh * 16;
        }
        av0 = *(const uint4*)p;
        av1 = *(const uint4*)(p + 8);
    };
    auto loadB = [&](int ks) {
        const uint4* p = (const uint4*)(wslab + (long)ks * 4096 + tid * 16);
        bv0 = p[0]; bv1 = p[1];
    };

    f32x4 acc[4][4];
#pragma unroll
    for (int m = 0; m < 4; ++m)
#pragma unroll
        for (int n = 0; n < 4; ++n)
#pragma unroll
            for (int k = 0; k < 4; ++k) acc[m][n][k] = 0.f;

    int kg = l >> 4, li = l & 15;
    loadA(0); loadB(0);
    for (int ks = 0; ks < KS; ++ks) {
        __syncthreads();                       // prior reads done
        *(uint4*)&As[(sh * 2) * 1024 + sr * 8]     = av0;
        *(uint4*)&As[(sh * 2 + 1) * 1024 + sr * 8] = av1;
        *(uint4*)&Bs[tid * 16]     = bv0;
        *(uint4*)&Bs[tid * 16 + 8] = bv1;
        __syncthreads();
        if (ks + 1 < KS) { loadA(ks + 1); loadB(ks + 1); }  // prefetch under MFMA
        bf16x8 af[4], bfr[4];
#pragma unroll
        for (int m = 0; m < 4; ++m)
            af[m] = *(const bf16x8*)&As[kg * 1024 + (wr * 64 + m * 16 + li) * 8];
#pragma unroll
        for (int n = 0; n < 4; ++n)
            bfr[n] = *(const bf16x8*)&Bs[kg * 1024 + (wc * 64 + n * 16 + li) * 8];
#pragma unroll
        for (int m = 0; m < 4; ++m)
#pragma unroll
            for (int n = 0; n < 4; ++n)
                acc[m][n] = __builtin_amdgcn_mfma_f32_16x16x32_bf16(af[m], bfr[n], acc[m][n], 0, 0, 0);
    }

    int jrow4 = (l >> 4) * 4;
    if (EP == 0) {                             // img_node
        float bi[4], bl[4], wl[4][5];
#pragma unroll
        for (int n = 0; n < 4; ++n) {
            int col = n0 + wc * 64 + n * 16 + li;
            bi[n] = bias[col]; bl[n] = bias2[col];
#pragma unroll
            for (int j5 = 0; j5 < 5; ++j5) wl[n][j5] = Wloc[j5 * H_ + col];
        }
#pragma unroll
        for (int m = 0; m < 4; ++m)
#pragma unroll
            for (int j = 0; j < 4; ++j) {
                int row = m0 + wr * 64 + m * 16 + jrow4 + j;
                int b = row / NO_, o = row - b * NO_;
                float lv[5];
#pragma unroll
                for (int j5 = 0; j5 < 5; ++j5) lv[j5] = loc[(long)row * 5 + j5];
#pragma unroll
                for (int n = 0; n < 4; ++n) {
                    int col = n0 + wc * 64 + n * 16 + li;
                    float val = acc[m][n][j] + bi[n];
                    out0[(long)row * H_ + col] = f2bf(val);
                    float nk = val + bl[n];
#pragma unroll
                    for (int j5 = 0; j5 < 5; ++j5) nk = fmaf(lv[j5], wl[n][j5], nk);
                    out1[((long)b * NN_ + o) * H_ + col] = f2bf(nk);
                }
            }
    } else if (EP == 1) {                      // img_edge
        float bi[4];
#pragma unroll
        for (int n = 0; n < 4; ++n) bi[n] = bias[n0 + wc * 64 + n * 16 + li];
#pragma unroll
        for (int m = 0; m < 4; ++m)
#pragma unroll
            for (int j = 0; j < 4; ++j) {
                int row = m0 + wr * 64 + m * 16 + jrow4 + j;
                int b = row / NE_, e = row - b * NE_;
#pragma unroll
                for (int n = 0; n < 4; ++n) {
                    int col = n0 + wc * 64 + n * 16 + li;
                    out0[((long)b * NEK_ + e) * H_ + col] = f2bf(acc[m][n][j] + bi[n]);
                }
            }
    } else {                                   // score partials
        float vv[4];
        int cols[4];
#pragma unroll
        for (int n = 0; n < 4; ++n) {
            cols[n] = n0 + wc * 64 + n * 16 + li;
            vv[n] = vvec[cols[n]];
        }
        int slot = nb * 2 + wc;
#pragma unroll
        for (int m = 0; m < 4; ++m)
#pragma unroll
            for (int j = 0; j < 4; ++j) {
                int row = m0 + wr * 64 + m * 16 + jrow4 + j;
                int b = row / Nrows;
                const float* qpb = qp + (long)b * H_;
                float p = 0.f;
#pragma unroll
                for (int n = 0; n < 4; ++n)
                    p += tanhf(qpb[cols[n]] + acc[m][n][j]) * vv[n];
                p += __shfl_xor(p, 1); p += __shfl_xor(p, 2);
                p += __shfl_xor(p, 4); p += __shfl_xor(p, 8);
                if (li == 0) sout[(long)slot * Mtot + row] = p;
            }
    }
}

// ---------------------------------------------------------------------------
// lang_encode with MFMA: 32 rows/block; pooled bf16 in LDS [40 kg][32 r][8];
// W_lang prep [4 nb][10 ks][4096]; 4 waves each own 128 cols.
template<int OUTF32>
__global__ __launch_bounds__(256) void lang_mfma_kernel(
    const int* __restrict__ tokens, int tok_stride, int tok_off,
    const float* __restrict__ embed, const short* __restrict__ Wp,
    const float* __restrict__ bias,
    void* __restrict__ out, int rows_per_b, long out_bstride, long out_roff,
    float* __restrict__ maskout, int nrows)
{
    __shared__ int   toks[32][8];
    __shared__ float rinv[32];
    __shared__ __align__(16) short Ap[40 * 32 * 8];   // 20 KB
    __shared__ __align__(16) short Bs[4 * 4096];      // 32 KB
    int tid = threadIdx.x;
    int base = blockIdx.x * 32;
    {
        int r = tid >> 3, tt = tid & 7;
        toks[r][tt] = tokens[tok_off + (long)(base + r) * tok_stride + tt];
    }
    __syncthreads();
    if (tid < 32) {
        int c = 0;
#pragma unroll
        for (int t = 0; t < 8; ++t) c += (toks[tid][t] != PAD_);
        rinv[tid] = 1.f / fmaxf((float)c, 1.f);
        if (maskout) maskout[base + tid] = (c > 0) ? 1.f : 0.f;
    }
    __syncthreads();

    for (int task = tid; task < 1280; task += 256) {
        int r = task / 40, kg = task - r * 40;
        float s[8] = {0.f,0.f,0.f,0.f,0.f,0.f,0.f,0.f};
        if (kg <= 37) {
#pragma unroll
            for (int t = 0; t < 8; ++t) {
                int tok = toks[r][t];
                if (tok != PAD_) {
                    const float* ep = embed + (long)tok * EMB_ + kg * 8;
                    float4 a = ldf4(ep);
                    s[0] += a.x; s[1] += a.y; s[2] += a.z; s[3] += a.w;
                    if (kg < 37) {
                        float4 b = ldf4(ep + 4);
                        s[4] += b.x; s[5] += b.y; s[6] += b.z; s[7] += b.w;
                    }
                }
            }
        }
        float iv = rinv[r];
        short o[8];
#pragma unroll
        for (int j = 0; j < 8; ++j) o[j] = f2bf(s[j] * iv);
        *(uint4*)&Ap[(kg * 32 + r) * 8] = *(uint4*)o;
    }

    int w = tid >> 6, l = tid & 63, kg = l >> 4, li = l & 15;
    f32x4 acc[2][8];
#pragma unroll
    for (int m = 0; m < 2; ++m)
#pragma unroll
        for (int n = 0; n < 8; ++n)
#pragma unroll
            for (int k = 0; k < 4; ++k) acc[m][n][k] = 0.f;

    for (int ks = 0; ks < 10; ++ks) {
        __syncthreads();
#pragma unroll
        for (int c = 0; c < 4; ++c) {
            int flat = c * 256 + tid;       // 1024 x 32B
            int nb = flat >> 8, rest = flat & 255;
            const uint4* p = (const uint4*)(Wp + (long)(nb * 10 + ks) * 4096 + rest * 16);
            uint4* q = (uint4*)&Bs[nb * 4096 + rest * 16];
            q[0] = p[0]; q[1] = p[1];
        }
        __syncthreads();
        bf16x8 af[2];
#pragma unroll
        for (int m = 0; m < 2; ++m)
            af[m] = *(const bf16x8*)&Ap[((ks * 4 + kg) * 32 + m * 16 + li) * 8];
#pragma unroll
        for (int n = 0; n < 8; ++n) {
            bf16x8 bf = *(const bf16x8*)&Bs[w * 4096 + kg * 1024 + (n * 16 + li) * 8];
#pragma unroll
            for (int m = 0; m < 2; ++m)
                acc[m][n] = __builtin_amdgcn_mfma_f32_16x16x32_bf16(af[m], bf, acc[m][n], 0, 0, 0);
        }
    }

#pragma unroll
    for (int m = 0; m < 2; ++m)
#pragma unroll
        for (int j = 0; j < 4; ++j) {
            int r = m * 16 + (l >> 4) * 4 + j;
            int i = base + r;
            if (i >= nrows) continue;
            int b = i / rows_per_b, k = i - b * rows_per_b;
#pragma unroll
            for (int n = 0; n < 8; ++n) {
                int col = w * 128 + n * 16 + li;
                float val = tanhf(acc[m][n][j] + bias[col]);
                long idx = (long)b * out_bstride + out_roff + (long)k * H_ + col;
                if (OUTF32) ((float*)out)[idx] = val;
                else        ((short*)out)[idx] = f2bf(val);
            }
        }
}

// ---------------------------------------------------------------------------
// softmax over N (summing 8 deterministic partials) then weighted sum of bf16
// keys -> out[b, 512]. grid (B, 2).
template<bool ADD, bool MASK>
__global__ __launch_bounds__(256) void attend_kernel(
    const float* __restrict__ sp, const short* __restrict__ keys,
    const float* __restrict__ maskbuf, float* __restrict__ outv, int N, int Mtot)
{
    __shared__ float sw[NEK_];
    __shared__ float red[256];
    int b = blockIdx.x, tid = threadIdx.x;

    float lmax = -3.0e38f;
    for (int n = tid; n < N; n += 256) {
        long row = (long)b * N + n;
        float x = 0.f;
#pragma unroll
        for (int s = 0; s < 8; ++s) x += sp[(long)s * Mtot + row];
        if (MASK && n >= NO_ && maskbuf[(long)b * NK_ + (n - NO_)] == 0.f) x = -1e30f;
        sw[n] = x;
        lmax = fmaxf(lmax, x);
    }
    red[tid] = lmax; __syncthreads();
    for (int st = 128; st > 0; st >>= 1) {
        if (tid < st) red[tid] = fmaxf(red[tid], red[tid + st]);
        __syncthreads();
    }
    float mx = red[0]; __syncthreads();

    float lsum = 0.f;
    for (int n = tid; n < N; n += 256) {
        float e = expf(sw[n] - mx);
        sw[n] = e;
        lsum += e;
    }
    red[tid] = lsum; __syncthreads();
    for (int st = 128; st > 0; st >>= 1) {
        if (tid < st) red[tid] += red[tid + st];
        __syncthreads();
    }
    float invZ = 1.0f / red[0];

    int col = blockIdx.y * 256 + tid;
    float a = 0.f;
#pragma unroll 4
    for (int n = 0; n < N; ++n)
        a = fmaf(sw[n], bf2f(keys[((long)b * N + n) * H_ + col]), a);
    a *= invZ;
    if (ADD) outv[(long)b * H_ + col] += a;
    else     outv[(long)b * H_ + col] = a;
}

// ---------------------------------------------------------------------------
// out[b,c] = act( in[b,:] @ W + bias )  — grid (B, ceil(C/256)), f32 path
template<int ACT>
__global__ __launch_bounds__(256) void bmatvec_kernel(
    const float* __restrict__ in, const float* __restrict__ W,
    const float* __restrict__ bias, float* __restrict__ outp, int E, int C)
{
    __shared__ float ins[512];
    int b = blockIdx.x, tid = threadIdx.x;
    for (int e = tid; e < E; e += 256) ins[e] = in[(long)b * E + e];
    __syncthreads();
    int c = blockIdx.y * 256 + tid;
    if (c >= C) return;
    float a = bias ? bias[c] : 0.0f;
#pragma unroll 4
    for (int e = 0; e < E; ++e) a = fmaf(ins[e], W[(long)e * C + c], a);
    if (ACT == 1) a = tanhf(a);
    outp[(long)b * C + c] = a;
}

// ---------------------------------------------------------------------------
extern "C" void kernel_launch(void* const* d_in, const int* in_sizes, int n_in,
                              void* d_out, int out_size, void* d_ws, size_t ws_size,
                              hipStream_t stream)
{
    (void)in_sizes; (void)n_in; (void)out_size; (void)ws_size;

    const float* img_feat  = (const float*)d_in[0];
    const float* img_loc   = (const float*)d_in[1];
    const int*   id1       = (const int*)d_in[2];
    const int*   id2       = (const int*)d_in[3];
    const int*   kg_entity = (const int*)d_in[4];
    const int*   kg_edge   = (const int*)d_in[7];
    const int*   r_nodes   = (const int*)d_in[8];
    const float* embed     = (const float*)d_in[11];
    const float* W_lang    = (const float*)d_in[12];
    const float* b_lang    = (const float*)d_in[13];
    const float* W_img     = (const float*)d_in[14];
    const float* b_img     = (const float*)d_in[15];
    const float* W_loc     = (const float*)d_in[16];
    const float* b_loc     = (const float*)d_in[17];
    const float* W_rel     = (const float*)d_in[18];
    const float* b_rel     = (const float*)d_in[19];
    const float* Wq_n      = (const float*)d_in[20];
    const float* Wk_n      = (const float*)d_in[21];
    const float* v_n       = (const float*)d_in[22];
    const float* Wq_e      = (const float*)d_in[23];
    const float* Wk_e      = (const float*)d_in[24];
    const float* v_e       = (const float*)d_in[25];
    const float* W1        = (const float*)d_in[26];
    const float* b1        = (const float*)d_in[27];
    const float* W2        = (const float*)d_in[28];
    const float* b2        = (const float*)d_in[29];
    float* out = (float*)d_out;

    char* ws = (char*)d_ws;
    size_t off = 0;
    auto allocS = [&](size_t n) { short* p = (short*)(ws + off); off += ((n * 2 + 255) & ~255ULL); return p; };
    auto allocF = [&](size_t n) { float* p = (float*)(ws + off); off += ((n * 4 + 255) & ~255ULL); return p; };

    short* img_feat_bf = allocS((size_t)B_ * NO_ * IMG_);      // 13 MB
    short* Wp_img      = allocS((size_t)4 * 64 * 4096);
    short* Wp_rel      = allocS((size_t)4 * 32 * 4096);
    short* Wp_kn       = allocS((size_t)4 * 16 * 4096);
    short* Wp_ke       = allocS((size_t)4 * 16 * 4096);
    short* Wp_lang     = allocS((size_t)4 * 10 * 4096);
    short* img_f_bf    = allocS((size_t)B_ * NO_ * H_);
    short* node_keys   = allocS((size_t)B_ * NN_ * H_);        // 36 MB
    short* edge_keys   = allocS((size_t)B_ * NEK_ * H_);       // 52 MB
    float* rfeat   = allocF((size_t)B_ * H_);
    float* qp_n    = allocF((size_t)B_ * H_);
    float* qp_e    = allocF((size_t)B_ * H_);
    float* mask_kg = allocF((size_t)B_ * NK_);
    float* sp_n    = allocF((size_t)8 * B_ * NN_);             // partials
    float* sp_e    = allocF((size_t)8 * B_ * NEK_);
    float* fin     = allocF((size_t)B_ * H_);
    float* hid     = allocF((size_t)B_ * H_);

    // --- weight prep + input conversion ---
    cvt_bf16_kernel<<<(B_ * NO_ * IMG_ / 8 + 255) / 256, 256, 0, stream>>>(
        img_feat, img_feat_bf, (long)B_ * NO_ * IMG_);
    wprep_kernel<<<512, 256, 0, stream>>>(W_img,  Wp_img,  IMG_, 64);
    wprep_kernel<<<256, 256, 0, stream>>>(W_rel,  Wp_rel,  1024, 32);
    wprep_kernel<<<128, 256, 0, stream>>>(Wk_n,   Wp_kn,   512,  16);
    wprep_kernel<<<128, 256, 0, stream>>>(Wk_e,   Wp_ke,   512,  16);
    wprep_kernel<<< 80, 256, 0, stream>>>(W_lang, Wp_lang, EMB_, 10);

    // --- language encodes ---
    lang_mfma_kernel<1><<<1, 256, 0, stream>>>(
        r_nodes, R_ * L_, (R_ - 1) * L_, embed, Wp_lang, b_lang,
        rfeat, 1, (long)H_, 0L, nullptr, B_);
    lang_mfma_kernel<0><<<B_ * NK_ / 32, 256, 0, stream>>>(
        kg_entity, L_, 0, embed, Wp_lang, b_lang,
        node_keys, NK_, (long)NN_ * H_, (long)NO_ * H_, mask_kg, B_ * NK_);
    lang_mfma_kernel<0><<<B_ * KE_ / 32, 256, 0, stream>>>(
        kg_edge, L_, 0, embed, Wp_lang, b_lang,
        edge_keys, KE_, (long)NEK_ * H_, (long)NE_ * H_, nullptr, B_ * KE_);

    // --- qp for root program node ---
    bmatvec_kernel<0><<<dim3(B_, 2), 256, 0, stream>>>(rfeat, Wq_n, nullptr, qp_n, H_, MID_);
    bmatvec_kernel<0><<<dim3(B_, 2), 256, 0, stream>>>(rfeat, Wq_e, nullptr, qp_e, H_, MID_);

    // --- image branches ---
    mfma_gemm_kernel<0, 0><<<dim3(B_ * NO_ / 128, 4), 256, 0, stream>>>(
        img_feat_bf, IMG_, Wp_img, 64, nullptr, nullptr, nullptr,
        b_img, b_loc, img_loc, W_loc, nullptr, nullptr,
        img_f_bf, node_keys, nullptr, 0, 0);
    mfma_gemm_kernel<2, 1><<<dim3(B_ * NE_ / 128, 4), 256, 0, stream>>>(
        nullptr, 0, Wp_rel, 32, id1, id2, img_f_bf,
        b_rel, nullptr, nullptr, nullptr, nullptr, nullptr,
        edge_keys, nullptr, nullptr, 0, 0);

    // --- fused keys@Wk + tanh-attention score partials ---
    mfma_gemm_kernel<0, 2><<<dim3(B_ * NN_ / 128, 4), 256, 0, stream>>>(
        node_keys, H_, Wp_kn, 16, nullptr, nullptr, nullptr,
        nullptr, nullptr, nullptr, nullptr, qp_n, v_n,
        nullptr, nullptr, sp_n, NN_, B_ * NN_);
    mfma_gemm_kernel<0, 2><<<dim3(B_ * NEK_ / 128, 4), 256, 0, stream>>>(
        edge_keys, H_, Wp_ke, 16, nullptr, nullptr, nullptr,
        nullptr, nullptr, nullptr, nullptr, qp_e, v_e,
        nullptr, nullptr, sp_e, NEK_, B_ * NEK_);

    // --- softmax + weighted sums ---
    attend_kernel<false, true ><<<dim3(B_, 2), 256, 0, stream>>>(
        sp_n, node_keys, mask_kg, fin, NN_, B_ * NN_);
    attend_kernel<true,  false><<<dim3(B_, 2), 256, 0, stream>>>(
        sp_e, edge_keys, nullptr, fin, NEK_, B_ * NEK_);

    // --- head ---
    bmatvec_kernel<1><<<dim3(B_, 2), 256, 0, stream>>>(fin, W1, b1, hid, H_, MID_);
    bmatvec_kernel<0><<<dim3(B_, (C_ + 255) / 256), 256, 0, stream>>>(hid, W2, b2, out, MID_, C_);
}